// Round 1
// baseline (1337.500 us; speedup 1.0000x reference)
//
#include <hip/hip_runtime.h>

typedef unsigned short u16;
typedef short short8 __attribute__((ext_vector_type(8)));
typedef float floatx4 __attribute__((ext_vector_type(4)));

#define H_ 4096
#define NH_ 32
#define NKV_ 8
#define HD_ 128
#define SEQ_ 2048
#define BATCH_ 2
#define ROWS_ (BATCH_*SEQ_)          // 4096
#define KVW_ (NKV_*HD_)              // 1024
#define SCALE_ 0.08838834764831845f  // 128^-0.5

__device__ __forceinline__ u16 f2bf(float f) {
  union { float f; unsigned u; } x; x.f = f;
  unsigned r = x.u + 0x7fffu + ((x.u >> 16) & 1u);   // RNE
  return (u16)(r >> 16);
}
__device__ __forceinline__ float bf2f(u16 h) {
  union { unsigned u; float f; } x; x.u = ((unsigned)h) << 16;
  return x.f;
}

// ---------------- fp32 -> bf16 convert ----------------
__global__ __launch_bounds__(256) void cvt_f32_bf16(const float* __restrict__ src,
                                                    u16* __restrict__ dst, int n4) {
  int i = blockIdx.x * 256 + threadIdx.x;
  if (i >= n4) return;
  float4 v = ((const float4*)src)[i];
  ushort4 o;
  o.x = f2bf(v.x); o.y = f2bf(v.y); o.z = f2bf(v.z); o.w = f2bf(v.w);
  ((ushort4*)dst)[i] = o;
}

// ---------------- GEMM: C[M,N] = A[M,K] * B[N,K]^T (+bias) ----------------
// m97 pattern: 128x128 tile, BK=32, 4 waves each doing 4x4 of 16x16x32 MFMA,
// global_load_lds width=16 staging (LDS layout = load order, no padding).
template<int BF16_OUT, int HAS_BIAS>
__global__ __launch_bounds__(256) void gemm_nt(const u16* __restrict__ A, const u16* __restrict__ B,
                                               const float* __restrict__ bias, void* __restrict__ Cout,
                                               int M, int N, int K)
{
  __shared__ __align__(16) u16 As[128*32];
  __shared__ __align__(16) u16 Bs[128*32];
  const int tid  = threadIdx.x;
  const int lane = tid & 63;
  const int wave = tid >> 6;
  const int ln   = lane & 15;
  const int quad = lane >> 4;
  const int m0 = blockIdx.y * 128;
  const int n0 = blockIdx.x * 128;
  const int wr = (wave >> 1) * 64;   // wave row offset in tile
  const int wc = (wave & 1) * 64;    // wave col offset in tile

  floatx4 zf = {0.f, 0.f, 0.f, 0.f};
  floatx4 acc[4][4];
#pragma unroll
  for (int i = 0; i < 4; ++i)
#pragma unroll
    for (int j = 0; j < 4; ++j) acc[i][j] = zf;

  for (int k0 = 0; k0 < K; k0 += 32) {
#pragma unroll
    for (int r = 0; r < 2; ++r) {
      int offu = r*4096 + wave*1024;        // wave-uniform byte offset into 8KB tile
      int off  = offu + lane*16;            // per-lane byte offset (hardware: base+lane*16)
      int row  = off >> 6;                  // 64B per row (32 bf16)
      int kel  = (off & 63) >> 1;
      const u16* srcA = A + (size_t)(m0+row)*K + k0 + kel;
      const u16* srcB = B + (size_t)(n0+row)*K + k0 + kel;
      __builtin_amdgcn_global_load_lds((const __attribute__((address_space(1))) void*)srcA,
          (__attribute__((address_space(3))) void*)((char*)As + offu), 16, 0, 0);
      __builtin_amdgcn_global_load_lds((const __attribute__((address_space(1))) void*)srcB,
          (__attribute__((address_space(3))) void*)((char*)Bs + offu), 16, 0, 0);
    }
    __syncthreads();   // compiler drains vmcnt before s_barrier

    short8 af[4], bfr[4];
#pragma unroll
    for (int i = 0; i < 4; ++i)
      af[i] = *(const short8*)&As[(wr + i*16 + ln)*32 + quad*8];
#pragma unroll
    for (int j = 0; j < 4; ++j)
      bfr[j] = *(const short8*)&Bs[(wc + j*16 + ln)*32 + quad*8];
#pragma unroll
    for (int i = 0; i < 4; ++i)
#pragma unroll
      for (int j = 0; j < 4; ++j)
        acc[i][j] = __builtin_amdgcn_mfma_f32_16x16x32_bf16(af[i], bfr[j], acc[i][j], 0, 0, 0);
    __syncthreads();   // protect LDS reuse next iteration
  }

#pragma unroll
  for (int i = 0; i < 4; ++i) {
#pragma unroll
    for (int j = 0; j < 4; ++j) {
      int row = m0 + wr + i*16 + quad*4;
      int col = n0 + wc + j*16 + ln;
      float bv_ = HAS_BIAS ? bias[col] : 0.f;
#pragma unroll
      for (int r = 0; r < 4; ++r) {
        float v = acc[i][j][r] + bv_;
        if (BF16_OUT) ((u16*)Cout)[(size_t)(row+r)*N + col] = f2bf(v);
        else          ((float*)Cout)[(size_t)(row+r)*N + col] = v;
      }
    }
  }
}

// ---------------- RoPE: x1=x[0::2], x2=x[1::2]; out = [x1*c - x2*s, x1*s + x2*c] ----------------
__global__ __launch_bounds__(256) void rope_kernel(const u16* __restrict__ X, u16* __restrict__ Y,
                                                   const float* __restrict__ cosb, const float* __restrict__ sinb,
                                                   int nheads, int total)
{
  int idx = blockIdx.x * 256 + threadIdx.x;
  if (idx >= total) return;
  int d = idx & 63;
  int t = idx >> 6;
  int hh = t % nheads;
  int row = t / nheads;          // b*SEQ + s
  int s = row & (SEQ_ - 1);
  size_t base = (size_t)row * (nheads * HD_) + hh * HD_;
  float x1 = bf2f(X[base + 2*d]);
  float x2 = bf2f(X[base + 2*d + 1]);
  float c  = cosb[s*64 + d];
  float sn = sinb[s*64 + d];
  Y[base + d]      = f2bf(x1*c - x2*sn);
  Y[base + 64 + d] = f2bf(x1*sn + x2*c);
}

// ---------------- Flash attention (GQA, no mask) ----------------
// grid = (SEQ/64, BATCH*NH). 4 waves x 16 q-rows. kv tiles of 64 keys.
__global__ __launch_bounds__(256) void attn_fwd(const u16* __restrict__ Q, const u16* __restrict__ K,
                                                const u16* __restrict__ V, u16* __restrict__ O)
{
  __shared__ __align__(16) u16 Ks[64*136];    // [key][d], stride 136 (pad for frag reads)
  __shared__ __align__(16) u16 Vt[128*72];    // [d][key], stride 72 (transposed V)
  __shared__ __align__(16) u16 Pl[4*16*72];   // per-wave P, [q in 0..15][key 0..63], stride 72
  const int tid  = threadIdx.x;
  const int lane = tid & 63;
  const int wave = tid >> 6;
  const int ln   = lane & 15;
  const int quad = lane >> 4;
  const int qt = blockIdx.x;          // q tile (64 rows)
  const int bh = blockIdx.y;
  const int b  = bh >> 5;
  const int h  = bh & 31;
  const int kvh = h >> 2;             // GQA: 4 q-heads per kv-head
  const int q0 = qt * 64;

  // preload Q fragments: A-layout, m=ln, k = kst*32 + quad*8 + j
  short8 qf[4];
  {
    const u16* qbase = Q + (size_t)(b*SEQ_ + q0 + wave*16 + ln) * H_ + h * HD_;
#pragma unroll
    for (int k = 0; k < 4; ++k)
      qf[k] = *(const short8*)(qbase + k*32 + quad*8);
  }

  floatx4 zf = {0.f, 0.f, 0.f, 0.f};
  floatx4 o[8];
#pragma unroll
  for (int j = 0; j < 8; ++j) o[j] = zf;
  float mrow[4] = {-1e30f, -1e30f, -1e30f, -1e30f};
  float lrow[4] = {0.f, 0.f, 0.f, 0.f};

  for (int s0 = 0; s0 < SEQ_; s0 += 64) {
    __syncthreads();   // previous iteration's LDS reads done
    // stage K tile: 64 keys x 128 d (coalesced 256B per 16 lanes)
#pragma unroll
    for (int i = 0; i < 4; ++i) {
      int c = tid + i*256;
      int key = c >> 4, dg = c & 15;
      const u16* src = K + (size_t)(b*SEQ_ + s0 + key) * KVW_ + kvh*HD_ + dg*8;
      *(int4*)&Ks[key*136 + dg*8] = *(const int4*)src;
    }
    // stage V transposed: Vt[d][key]
#pragma unroll
    for (int i = 0; i < 4; ++i) {
      int c = tid + i*256;
      int key = c & 63, dg = c >> 6;
      const u16* src = V + (size_t)(b*SEQ_ + s0 + key) * KVW_ + kvh*HD_ + dg*8;
      union { int4 v; u16 u[8]; } w;
      w.v = *(const int4*)src;
#pragma unroll
      for (int jj = 0; jj < 8; ++jj)
        Vt[(dg*8 + jj)*72 + key] = w.u[jj];
    }
    __syncthreads();

    // S = Q K^T  (16 q x 64 keys per wave)
    floatx4 s[4];
#pragma unroll
    for (int nt = 0; nt < 4; ++nt) s[nt] = zf;
#pragma unroll
    for (int kst = 0; kst < 4; ++kst) {
#pragma unroll
      for (int nt = 0; nt < 4; ++nt) {
        short8 kf = *(const short8*)&Ks[(nt*16 + ln)*136 + kst*32 + quad*8];
        s[nt] = __builtin_amdgcn_mfma_f32_16x16x32_bf16(qf[kst], kf, s[nt], 0, 0, 0);
      }
    }
#pragma unroll
    for (int nt = 0; nt < 4; ++nt) s[nt] *= SCALE_;

    // online softmax: row = quad*4 + r, spread over 16 lanes (ln = key)
#pragma unroll
    for (int r = 0; r < 4; ++r) {
      float rm = fmaxf(fmaxf(s[0][r], s[1][r]), fmaxf(s[2][r], s[3][r]));
      rm = fmaxf(rm, __shfl_xor(rm, 1));
      rm = fmaxf(rm, __shfl_xor(rm, 2));
      rm = fmaxf(rm, __shfl_xor(rm, 4));
      rm = fmaxf(rm, __shfl_xor(rm, 8));
      float mn = fmaxf(mrow[r], rm);
      float alpha = __expf(mrow[r] - mn);
      mrow[r] = mn;
      float rs = 0.f;
#pragma unroll
      for (int nt = 0; nt < 4; ++nt) {
        float p = __expf(s[nt][r] - mn);
        s[nt][r] = p;
        rs += p;
      }
      rs += __shfl_xor(rs, 1);
      rs += __shfl_xor(rs, 2);
      rs += __shfl_xor(rs, 4);
      rs += __shfl_xor(rs, 8);
      lrow[r] = lrow[r] * alpha + rs;
#pragma unroll
      for (int j = 0; j < 8; ++j) o[j][r] *= alpha;
      // write P (C-layout -> LDS) for A-layout re-read
#pragma unroll
      for (int nt = 0; nt < 4; ++nt)
        Pl[wave*16*72 + (quad*4 + r)*72 + nt*16 + ln] = f2bf(s[nt][r]);
    }
    __syncthreads();   // P visible across lanes (and uniform across waves)

    // O += P V   (A = P[q][key], B = V[key][d] read from Vt[d][key])
#pragma unroll
    for (int k2 = 0; k2 < 2; ++k2) {
      short8 pf = *(const short8*)&Pl[wave*16*72 + ln*72 + k2*32 + quad*8];
#pragma unroll
      for (int j = 0; j < 8; ++j) {
        short8 vf = *(const short8*)&Vt[(j*16 + ln)*72 + k2*32 + quad*8];
        o[j] = __builtin_amdgcn_mfma_f32_16x16x32_bf16(pf, vf, o[j], 0, 0, 0);
      }
    }
  }

  // epilogue: O /= l, write (b, s, h*128+d)
#pragma unroll
  for (int r = 0; r < 4; ++r) {
    float inv = 1.f / lrow[r];
    size_t row = (size_t)(b*SEQ_ + q0 + wave*16 + quad*4 + r);
    u16* dst = O + row * H_ + h * HD_ + ln;
#pragma unroll
    for (int j = 0; j < 8; ++j)
      dst[j*16] = f2bf(o[j][r] * inv);
  }
}

// ---------------- host ----------------
extern "C" void kernel_launch(void* const* d_in, const int* in_sizes, int n_in,
                              void* d_out, int out_size, void* d_ws, size_t ws_size,
                              hipStream_t stream) {
  const float* hs   = (const float*)d_in[0];
  const float* cosb = (const float*)d_in[1];
  const float* sinb = (const float*)d_in[2];
  const float* Wq   = (const float*)d_in[3];
  const float* Wk   = (const float*)d_in[4];
  const float* bk   = (const float*)d_in[5];
  const float* Wv   = (const float*)d_in[6];
  const float* bv   = (const float*)d_in[7];
  const float* Wo   = (const float*)d_in[8];
  float* out = (float*)d_out;

  char* ws = (char*)d_ws;
  u16* hs_bf = (u16*)(ws +         0);  // 33554432 B
  u16* Wq_bf = (u16*)(ws +  33554432);  // 33554432
  u16* Wo_bf = (u16*)(ws +  67108864);  // 33554432
  u16* Wk_bf = (u16*)(ws + 100663296);  //  8388608
  u16* Wv_bf = (u16*)(ws + 109051904);  //  8388608
  u16* Q0    = (u16*)(ws + 117440512);  // 33554432
  u16* Qr    = (u16*)(ws + 150994944);  // 33554432
  u16* K0    = (u16*)(ws + 184549376);  //  8388608
  u16* Kr    = (u16*)(ws + 192937984);  //  8388608
  u16* Vb    = (u16*)(ws + 201326592);  //  8388608
  u16* Oa    = (u16*)(ws + 209715200);  // 33554432  -> total 243269632 B

  // converts
  {
    int n;
    n = ROWS_*H_;  cvt_f32_bf16<<<(n/4 + 255)/256, 256, 0, stream>>>(hs, hs_bf, n/4);
    n = H_*H_;     cvt_f32_bf16<<<(n/4 + 255)/256, 256, 0, stream>>>(Wq, Wq_bf, n/4);
    n = KVW_*H_;   cvt_f32_bf16<<<(n/4 + 255)/256, 256, 0, stream>>>(Wk, Wk_bf, n/4);
    n = KVW_*H_;   cvt_f32_bf16<<<(n/4 + 255)/256, 256, 0, stream>>>(Wv, Wv_bf, n/4);
    n = H_*H_;     cvt_f32_bf16<<<(n/4 + 255)/256, 256, 0, stream>>>(Wo, Wo_bf, n/4);
  }

  dim3 blk(256);
  // Q = hs @ Wq^T
  gemm_nt<1,0><<<dim3(H_/128,   ROWS_/128), blk, 0, stream>>>(hs_bf, Wq_bf, nullptr, Q0, ROWS_, H_,   H_);
  // K = hs @ Wk^T + bk ; V = hs @ Wv^T + bv
  gemm_nt<1,1><<<dim3(KVW_/128, ROWS_/128), blk, 0, stream>>>(hs_bf, Wk_bf, bk,      K0, ROWS_, KVW_, H_);
  gemm_nt<1,1><<<dim3(KVW_/128, ROWS_/128), blk, 0, stream>>>(hs_bf, Wv_bf, bv,      Vb, ROWS_, KVW_, H_);
  // RoPE
  rope_kernel<<<(ROWS_*NH_*64)/256,  256, 0, stream>>>(Q0, Qr, cosb, sinb, NH_,  ROWS_*NH_*64);
  rope_kernel<<<(ROWS_*NKV_*64)/256, 256, 0, stream>>>(K0, Kr, cosb, sinb, NKV_, ROWS_*NKV_*64);
  // attention
  attn_fwd<<<dim3(SEQ_/64, BATCH_*NH_), blk, 0, stream>>>(Qr, Kr, Vb, Oa);
  // out = O @ Wo^T (fp32 out)
  gemm_nt<0,0><<<dim3(H_/128, ROWS_/128), blk, 0, stream>>>(Oa, Wo_bf, nullptr, out, ROWS_, H_, H_);
}

// Round 2
// 1336.378 us; speedup vs baseline: 1.0008x; 1.0008x over previous
//
#include <hip/hip_runtime.h>

typedef unsigned short u16;
typedef short short8 __attribute__((ext_vector_type(8)));
typedef float floatx4 __attribute__((ext_vector_type(4)));

#define H_ 4096
#define NH_ 32
#define NKV_ 8
#define HD_ 128
#define SEQ_ 2048
#define BATCH_ 2
#define ROWS_ (BATCH_*SEQ_)          // 4096
#define KVW_ (NKV_*HD_)              // 1024
#define SCALE_ 0.08838834764831845f  // 128^-0.5
#define TSCALE_ (SCALE_*1.442695040888963f)   // fold log2e -> use exp2

__device__ __forceinline__ u16 f2bf(float f) {
  union { float f; unsigned u; } x; x.f = f;
  unsigned r = x.u + 0x7fffu + ((x.u >> 16) & 1u);   // RNE
  return (u16)(r >> 16);
}
__device__ __forceinline__ float bf2f(u16 h) {
  union { unsigned u; float f; } x; x.u = ((unsigned)h) << 16;
  return x.f;
}

// ---------------- fp32 -> bf16 convert ----------------
__global__ __launch_bounds__(256) void cvt_f32_bf16(const float* __restrict__ src,
                                                    u16* __restrict__ dst, int n4) {
  int i = blockIdx.x * 256 + threadIdx.x;
  if (i >= n4) return;
  float4 v = ((const float4*)src)[i];
  ushort4 o;
  o.x = f2bf(v.x); o.y = f2bf(v.y); o.z = f2bf(v.z); o.w = f2bf(v.w);
  ((ushort4*)dst)[i] = o;
}

// ---------------- GEMM: C[M,N] = A[M,K] * B[N,K]^T (+bias) ----------------
template<int BF16_OUT, int HAS_BIAS>
__global__ __launch_bounds__(256) void gemm_nt(const u16* __restrict__ A, const u16* __restrict__ B,
                                               const float* __restrict__ bias, void* __restrict__ Cout,
                                               int M, int N, int K)
{
  __shared__ __align__(16) u16 As[128*32];
  __shared__ __align__(16) u16 Bs[128*32];
  const int tid  = threadIdx.x;
  const int lane = tid & 63;
  const int wave = tid >> 6;
  const int ln   = lane & 15;
  const int quad = lane >> 4;
  const int m0 = blockIdx.y * 128;
  const int n0 = blockIdx.x * 128;
  const int wr = (wave >> 1) * 64;
  const int wc = (wave & 1) * 64;

  floatx4 zf = {0.f, 0.f, 0.f, 0.f};
  floatx4 acc[4][4];
#pragma unroll
  for (int i = 0; i < 4; ++i)
#pragma unroll
    for (int j = 0; j < 4; ++j) acc[i][j] = zf;

  for (int k0 = 0; k0 < K; k0 += 32) {
#pragma unroll
    for (int r = 0; r < 2; ++r) {
      int offu = r*4096 + wave*1024;
      int off  = offu + lane*16;
      int row  = off >> 6;
      int kel  = (off & 63) >> 1;
      const u16* srcA = A + (size_t)(m0+row)*K + k0 + kel;
      const u16* srcB = B + (size_t)(n0+row)*K + k0 + kel;
      __builtin_amdgcn_global_load_lds((const __attribute__((address_space(1))) void*)srcA,
          (__attribute__((address_space(3))) void*)((char*)As + offu), 16, 0, 0);
      __builtin_amdgcn_global_load_lds((const __attribute__((address_space(1))) void*)srcB,
          (__attribute__((address_space(3))) void*)((char*)Bs + offu), 16, 0, 0);
    }
    __syncthreads();

    short8 af[4], bfr[4];
#pragma unroll
    for (int i = 0; i < 4; ++i)
      af[i] = *(const short8*)&As[(wr + i*16 + ln)*32 + quad*8];
#pragma unroll
    for (int j = 0; j < 4; ++j)
      bfr[j] = *(const short8*)&Bs[(wc + j*16 + ln)*32 + quad*8];
#pragma unroll
    for (int i = 0; i < 4; ++i)
#pragma unroll
      for (int j = 0; j < 4; ++j)
        acc[i][j] = __builtin_amdgcn_mfma_f32_16x16x32_bf16(af[i], bfr[j], acc[i][j], 0, 0, 0);
    __syncthreads();
  }

#pragma unroll
  for (int i = 0; i < 4; ++i) {
#pragma unroll
    for (int j = 0; j < 4; ++j) {
      int row = m0 + wr + i*16 + quad*4;
      int col = n0 + wc + j*16 + ln;
      float bv_ = HAS_BIAS ? bias[col] : 0.f;
#pragma unroll
      for (int r = 0; r < 4; ++r) {
        float v = acc[i][j][r] + bv_;
        if (BF16_OUT) ((u16*)Cout)[(size_t)(row+r)*N + col] = f2bf(v);
        else          ((float*)Cout)[(size_t)(row+r)*N + col] = v;
      }
    }
  }
}

// ---------------- RoPE ----------------
__global__ __launch_bounds__(256) void rope_kernel(const u16* __restrict__ X, u16* __restrict__ Y,
                                                   const float* __restrict__ cosb, const float* __restrict__ sinb,
                                                   int nheads, int total)
{
  int idx = blockIdx.x * 256 + threadIdx.x;
  if (idx >= total) return;
  int d = idx & 63;
  int t = idx >> 6;
  int hh = t % nheads;
  int row = t / nheads;
  int s = row & (SEQ_ - 1);
  size_t base = (size_t)row * (nheads * HD_) + hh * HD_;
  float x1 = bf2f(X[base + 2*d]);
  float x2 = bf2f(X[base + 2*d + 1]);
  float c  = cosb[s*64 + d];
  float sn = sinb[s*64 + d];
  Y[base + d]      = f2bf(x1*c - x2*sn);
  Y[base + 64 + d] = f2bf(x1*sn + x2*c);
}

// ---------------- Flash attention (GQA, no mask) ----------------
// grid = (SEQ/128, BATCH*NH). 4 waves x 32 q-rows (2 m-tiles). kv tiles of 64 keys.
// Key-dim permutation kappa = (key&15)*4 + (key>>4) applied identically to P and Vt
// so P can be written as b64 per (m,r) and Vt staged with b64 register-transpose.
// K staged via global_load_lds with XOR swizzle dgp = dgl ^ (key&15) (conflict-free frag reads).
// Row-sum l computed by MFMA with an in-register ones B-frag (col 0).
__global__ __launch_bounds__(256, 3) void attn_fwd(const u16* __restrict__ Q, const u16* __restrict__ K,
                                                   const u16* __restrict__ V, u16* __restrict__ O)
{
  __shared__ __align__(16) u16 Ks[64*128];     // [key][dgp swizzled], 256B rows, 16 KB
  __shared__ __align__(16) u16 Vt[128*72];     // [d][kappa], stride 72, 18 KB
  __shared__ __align__(16) u16 Pl[4*32*72];    // per-wave [q 0..31][kappa], stride 72, 18 KB
  const int tid  = threadIdx.x;
  const int lane = tid & 63;
  const int wave = tid >> 6;
  const int ln   = lane & 15;
  const int quad = lane >> 4;
  const int bh = blockIdx.y;
  const int b  = bh >> 5;
  const int h  = bh & 31;
  const int kvh = h >> 2;
  const int q0 = blockIdx.x * 128;

  // Q fragments: A-layout, m = ln, k = kst*32 + quad*8 + j
  short8 qf[2][4];
#pragma unroll
  for (int mt = 0; mt < 2; ++mt) {
    const u16* qbase = Q + (size_t)(b*SEQ_ + q0 + wave*32 + mt*16 + ln) * H_ + h * HD_;
#pragma unroll
    for (int kst = 0; kst < 4; ++kst)
      qf[mt][kst] = *(const short8*)(qbase + kst*32 + quad*8);
  }

  // ones B-frag: B[k][n] = (n==0) ? 1 : 0  -> lanes with ln==0 hold bf16 1.0
  short8 bones;
  {
    short v1 = (ln == 0) ? (short)0x3F80 : (short)0;
#pragma unroll
    for (int j = 0; j < 8; ++j) bones[j] = v1;
  }

  floatx4 zf = {0.f, 0.f, 0.f, 0.f};
  floatx4 o[2][8];
  floatx4 ol[2];
#pragma unroll
  for (int mt = 0; mt < 2; ++mt) {
    ol[mt] = zf;
#pragma unroll
    for (int jt = 0; jt < 8; ++jt) o[mt][jt] = zf;
  }
  float mrow[2][4];
#pragma unroll
  for (int mt = 0; mt < 2; ++mt)
#pragma unroll
    for (int r = 0; r < 4; ++r) mrow[mt][r] = -1e30f;

  for (int s0 = 0; s0 < SEQ_; s0 += 64) {
    __syncthreads();   // all waves done reading Ks/Vt/Pl from previous tile
    // ---- stage K: global_load_lds, XOR-swizzled source ----
#pragma unroll
    for (int i = 0; i < 4; ++i) {
      int ou = wave*4096 + i*1024;          // wave-uniform LDS byte offset
      int ob = ou + lane*16;                // this lane's dest byte
      int key = ob >> 8;                    // 256 B per key row
      int dgp = (ob >> 4) & 15;
      int dgl = dgp ^ (key & 15);
      const u16* src = K + (size_t)(b*SEQ_ + s0 + key)*KVW_ + kvh*HD_ + dgl*8;
      __builtin_amdgcn_global_load_lds((const __attribute__((address_space(1))) void*)src,
          (__attribute__((address_space(3))) void*)((char*)Ks + ou), 16, 0, 0);
    }
    // ---- stage V transposed into kappa order (register transpose, b64 writes) ----
    {
      int g  = tid & 15;     // kappa group: kappa in [g*4, g*4+4) <-> keys j*16+g
      int dg = tid >> 4;     // d group (8 d's)
      union { int4 v; u16 u[8]; } w[4];
#pragma unroll
      for (int j = 0; j < 4; ++j)
        w[j].v = *(const int4*)(V + (size_t)(b*SEQ_ + s0 + j*16 + g)*KVW_ + kvh*HD_ + dg*8);
#pragma unroll
      for (int dd = 0; dd < 8; ++dd) {
        ushort4 t;
        t.x = w[0].u[dd]; t.y = w[1].u[dd]; t.z = w[2].u[dd]; t.w = w[3].u[dd];
        *(ushort4*)&Vt[(dg*8 + dd)*72 + g*4] = t;
      }
    }
    __syncthreads();

    // ---- S = Q K^T : K-frags shared across both m-tiles ----
    floatx4 s[2][4];
#pragma unroll
    for (int nt = 0; nt < 4; ++nt) { s[0][nt] = zf; s[1][nt] = zf; }
#pragma unroll
    for (int kst = 0; kst < 4; ++kst) {
      int dgp = (kst*4 + quad) ^ ln;
#pragma unroll
      for (int nt = 0; nt < 4; ++nt) {
        short8 kf = *(const short8*)&Ks[(nt*16 + ln)*128 + dgp*8];
        s[0][nt] = __builtin_amdgcn_mfma_f32_16x16x32_bf16(qf[0][kst], kf, s[0][nt], 0, 0, 0);
        s[1][nt] = __builtin_amdgcn_mfma_f32_16x16x32_bf16(qf[1][kst], kf, s[1][nt], 0, 0, 0);
      }
    }

    // ---- online softmax (t-domain: scaled by SCALE*log2e, exp2) ----
#pragma unroll
    for (int mt = 0; mt < 2; ++mt) {
#pragma unroll
      for (int r = 0; r < 4; ++r) {
        float rm = fmaxf(fmaxf(s[mt][0][r], s[mt][1][r]), fmaxf(s[mt][2][r], s[mt][3][r]));
        rm *= TSCALE_;
        rm = fmaxf(rm, __shfl_xor(rm, 1));
        rm = fmaxf(rm, __shfl_xor(rm, 2));
        rm = fmaxf(rm, __shfl_xor(rm, 4));
        rm = fmaxf(rm, __shfl_xor(rm, 8));
        float mn = fmaxf(mrow[mt][r], rm);
        float alpha = exp2f(mrow[mt][r] - mn);
        mrow[mt][r] = mn;
#pragma unroll
        for (int jt = 0; jt < 8; ++jt) o[mt][jt][r] *= alpha;
        ol[mt][r] *= alpha;
        ushort4 pw;
        pw.x = f2bf(exp2f(fmaf(s[mt][0][r], TSCALE_, -mn)));
        pw.y = f2bf(exp2f(fmaf(s[mt][1][r], TSCALE_, -mn)));
        pw.z = f2bf(exp2f(fmaf(s[mt][2][r], TSCALE_, -mn)));
        pw.w = f2bf(exp2f(fmaf(s[mt][3][r], TSCALE_, -mn)));
        // kappa = ln*4 + nt : one b64 write covers this lane's 4 P values
        *(ushort4*)&Pl[wave*2304 + (mt*16 + quad*4 + r)*72 + ln*4] = pw;
      }
    }
    // no barrier needed: each wave reads back only its own Pl slice (lgkmcnt ordering)

    // ---- O += P V (contraction over kappa; V-frags shared across m-tiles) ----
#pragma unroll
    for (int k2 = 0; k2 < 2; ++k2) {
      short8 pf0 = *(const short8*)&Pl[wave*2304 + (ln)*72      + k2*32 + quad*8];
      short8 pf1 = *(const short8*)&Pl[wave*2304 + (16 + ln)*72 + k2*32 + quad*8];
#pragma unroll
      for (int jt = 0; jt < 8; ++jt) {
        short8 vf = *(const short8*)&Vt[(jt*16 + ln)*72 + k2*32 + quad*8];
        o[0][jt] = __builtin_amdgcn_mfma_f32_16x16x32_bf16(pf0, vf, o[0][jt], 0, 0, 0);
        o[1][jt] = __builtin_amdgcn_mfma_f32_16x16x32_bf16(pf1, vf, o[1][jt], 0, 0, 0);
      }
      ol[0] = __builtin_amdgcn_mfma_f32_16x16x32_bf16(pf0, bones, ol[0], 0, 0, 0);
      ol[1] = __builtin_amdgcn_mfma_f32_16x16x32_bf16(pf1, bones, ol[1], 0, 0, 0);
    }
  }

  // ---- epilogue: broadcast l from ln==0 lane of each quad, divide, store ----
#pragma unroll
  for (int mt = 0; mt < 2; ++mt) {
#pragma unroll
    for (int r = 0; r < 4; ++r) {
      float lv = __shfl(ol[mt][r], lane & 48);
      float inv = 1.f / lv;
      size_t row = (size_t)(b*SEQ_ + q0 + wave*32 + mt*16 + quad*4 + r);
      u16* dst = O + row * H_ + h * HD_ + ln;
#pragma unroll
      for (int jt = 0; jt < 8; ++jt)
        dst[jt*16] = f2bf(o[mt][jt][r] * inv);
    }
  }
}

// ---------------- host ----------------
extern "C" void kernel_launch(void* const* d_in, const int* in_sizes, int n_in,
                              void* d_out, int out_size, void* d_ws, size_t ws_size,
                              hipStream_t stream) {
  const float* hs   = (const float*)d_in[0];
  const float* cosb = (const float*)d_in[1];
  const float* sinb = (const float*)d_in[2];
  const float* Wq   = (const float*)d_in[3];
  const float* Wk   = (const float*)d_in[4];
  const float* bk   = (const float*)d_in[5];
  const float* Wv   = (const float*)d_in[6];
  const float* bv   = (const float*)d_in[7];
  const float* Wo   = (const float*)d_in[8];
  float* out = (float*)d_out;

  char* ws = (char*)d_ws;
  u16* hs_bf = (u16*)(ws +         0);  // 33554432 B
  u16* Wq_bf = (u16*)(ws +  33554432);  // 33554432
  u16* Wo_bf = (u16*)(ws +  67108864);  // 33554432
  u16* Wk_bf = (u16*)(ws + 100663296);  //  8388608
  u16* Wv_bf = (u16*)(ws + 109051904);  //  8388608
  u16* Q0    = (u16*)(ws + 117440512);  // 33554432
  u16* Qr    = (u16*)(ws + 150994944);  // 33554432
  u16* K0    = (u16*)(ws + 184549376);  //  8388608
  u16* Kr    = (u16*)(ws + 192937984);  //  8388608
  u16* Vb    = (u16*)(ws + 201326592);  //  8388608
  u16* Oa    = (u16*)(ws + 209715200);  // 33554432

  {
    int n;
    n = ROWS_*H_;  cvt_f32_bf16<<<(n/4 + 255)/256, 256, 0, stream>>>(hs, hs_bf, n/4);
    n = H_*H_;     cvt_f32_bf16<<<(n/4 + 255)/256, 256, 0, stream>>>(Wq, Wq_bf, n/4);
    n = KVW_*H_;   cvt_f32_bf16<<<(n/4 + 255)/256, 256, 0, stream>>>(Wk, Wk_bf, n/4);
    n = KVW_*H_;   cvt_f32_bf16<<<(n/4 + 255)/256, 256, 0, stream>>>(Wv, Wv_bf, n/4);
    n = H_*H_;     cvt_f32_bf16<<<(n/4 + 255)/256, 256, 0, stream>>>(Wo, Wo_bf, n/4);
  }

  dim3 blk(256);
  gemm_nt<1,0><<<dim3(H_/128,   ROWS_/128), blk, 0, stream>>>(hs_bf, Wq_bf, nullptr, Q0, ROWS_, H_,   H_);
  gemm_nt<1,1><<<dim3(KVW_/128, ROWS_/128), blk, 0, stream>>>(hs_bf, Wk_bf, bk,      K0, ROWS_, KVW_, H_);
  gemm_nt<1,1><<<dim3(KVW_/128, ROWS_/128), blk, 0, stream>>>(hs_bf, Wv_bf, bv,      Vb, ROWS_, KVW_, H_);
  rope_kernel<<<(ROWS_*NH_*64)/256,  256, 0, stream>>>(Q0, Qr, cosb, sinb, NH_,  ROWS_*NH_*64);
  rope_kernel<<<(ROWS_*NKV_*64)/256, 256, 0, stream>>>(K0, Kr, cosb, sinb, NKV_, ROWS_*NKV_*64);
  attn_fwd<<<dim3(SEQ_/128, BATCH_*NH_), blk, 0, stream>>>(Qr, Kr, Vb, Oa);
  gemm_nt<0,0><<<dim3(H_/128, ROWS_/128), blk, 0, stream>>>(Oa, Wo_bf, nullptr, out, ROWS_, H_, H_);
}